// Round 2
// baseline (1268.369 us; speedup 1.0000x reference)
//
#include <hip/hip_runtime.h>

typedef _Float16 half8_t __attribute__((ext_vector_type(8)));
typedef _Float16 half2_t __attribute__((ext_vector_type(2)));
typedef float floatx4 __attribute__((ext_vector_type(4)));

#define B_DIM 256
#define T_DIM 512
#define E_DIM 256
#define H_DIM 256
#define MROWS (B_DIM * T_DIM)  // 131072 rows of [B*T, E]

__device__ __forceinline__ half2_t cvt2(float x, float y) {
    half2_t v; v[0] = (_Float16)x; v[1] = (_Float16)y; return v;
}

__device__ __forceinline__ float fdot2f(half2_t a, half2_t b, float c) {
#if __has_builtin(__builtin_amdgcn_fdot2)
    return __builtin_amdgcn_fdot2(a, b, c, false);
#else
    return c + (float)a[0] * (float)b[0] + (float)a[1] * (float)b[1];
#endif
}

// quad_perm DPP cross-lane (within each group of 4 lanes) — VALU, no LDS pipe.
// xor1: [1,0,3,2] -> ctrl 0xB1 ; xor2: [2,3,0,1] -> ctrl 0x4E
__device__ __forceinline__ float dpp_xor1(float x) {
#if __has_builtin(__builtin_amdgcn_mov_dpp)
    int i = __builtin_bit_cast(int, x);
    i = __builtin_amdgcn_mov_dpp(i, 0xB1, 0xF, 0xF, true);
    return __builtin_bit_cast(float, i);
#else
    return __shfl_xor(x, 1);
#endif
}
__device__ __forceinline__ float dpp_xor2(float x) {
#if __has_builtin(__builtin_amdgcn_mov_dpp)
    int i = __builtin_bit_cast(int, x);
    i = __builtin_amdgcn_mov_dpp(i, 0x4E, 0xF, 0xF, true);
    return __builtin_bit_cast(float, i);
#else
    return __shfl_xor(x, 2);
#endif
}

__device__ __forceinline__ float fast_rcp(float x) {
#if __has_builtin(__builtin_amdgcn_rcpf)
    return __builtin_amdgcn_rcpf(x);
#else
    return 1.0f / x;
#endif
}

// ---------------------------------------------------------------------------
// Phase 1: X[m][n] = emb[m][:E] . Wg[n][:E] + bg[n]  for gates g in {z,r,m}
//   gate 0 -> Xz (f16, ws), gate 1 -> Xr (f16, ws), gate 2 -> Xm (f32, d_out)
// ---------------------------------------------------------------------------
__global__ __launch_bounds__(256, 2) void gemm_x(
    const float* __restrict__ emb,
    const float* __restrict__ Wz, const float* __restrict__ bz,
    const float* __restrict__ Wr, const float* __restrict__ br,
    const float* __restrict__ Wm, const float* __restrict__ bm,
    _Float16* __restrict__ Xz, _Float16* __restrict__ Xr,
    float* __restrict__ Xm)
{
    const int n0 = blockIdx.x * 128;
    const int m0 = blockIdx.y * 128;
    const int gate = n0 >> 8;
    const int ng0 = n0 & 255;
    const float* W    = (gate == 0) ? Wz : (gate == 1) ? Wr : Wm;
    const float* bias = (gate == 0) ? bz : (gate == 1) ? br : bm;

    __shared__ __align__(16) _Float16 lA[128 * 40];
    __shared__ __align__(16) _Float16 lB[128 * 40];

    const int t = threadIdx.x;
    const int lane = t & 63;
    const int wave = t >> 6;
    const int wm = (wave >> 1) * 64;
    const int wn = (wave & 1) * 64;
    const int lq = lane >> 4;
    const int lr = lane & 15;

    floatx4 acc[4][4];
    #pragma unroll
    for (int i = 0; i < 4; ++i)
        #pragma unroll
        for (int j = 0; j < 4; ++j)
            acc[i][j] = (floatx4)0.0f;

    const int srow = t >> 1;
    const int scol = (t & 1) * 16;
    const float* aSrc = emb + (size_t)(m0 + srow) * E_DIM + scol;
    const float* bSrc = W + (size_t)(ng0 + srow) * (E_DIM + H_DIM) + scol;

    for (int k0 = 0; k0 < E_DIM; k0 += 32) {
        float ta[16], tb[16];
        #pragma unroll
        for (int u = 0; u < 4; ++u) {
            *(float4*)(ta + 4 * u) = *(const float4*)(aSrc + k0 + 4 * u);
            *(float4*)(tb + 4 * u) = *(const float4*)(bSrc + k0 + 4 * u);
        }
        half8_t a0, a1, b0, b1;
        #pragma unroll
        for (int u = 0; u < 8; ++u) {
            a0[u] = (_Float16)ta[u]; a1[u] = (_Float16)ta[u + 8];
            b0[u] = (_Float16)tb[u]; b1[u] = (_Float16)tb[u + 8];
        }
        __syncthreads();
        *(half8_t*)&lA[srow * 40 + scol]     = a0;
        *(half8_t*)&lA[srow * 40 + scol + 8] = a1;
        *(half8_t*)&lB[srow * 40 + scol]     = b0;
        *(half8_t*)&lB[srow * 40 + scol + 8] = b1;
        __syncthreads();

        half8_t af[4], bf[4];
        #pragma unroll
        for (int i = 0; i < 4; ++i)
            af[i] = *(const half8_t*)&lA[(wm + i * 16 + lr) * 40 + lq * 8];
        #pragma unroll
        for (int j = 0; j < 4; ++j)
            bf[j] = *(const half8_t*)&lB[(wn + j * 16 + lr) * 40 + lq * 8];
        #pragma unroll
        for (int i = 0; i < 4; ++i)
            #pragma unroll
            for (int j = 0; j < 4; ++j)
                acc[i][j] = __builtin_amdgcn_mfma_f32_16x16x32_f16(
                    af[i], bf[j], acc[i][j], 0, 0, 0);
    }

    if (gate < 2) {
        _Float16* dst = (gate == 0) ? Xz : Xr;
        #pragma unroll
        for (int j = 0; j < 4; ++j) {
            const int ng = ng0 + wn + j * 16 + lr;
            const float bv = bias[ng];
            #pragma unroll
            for (int i = 0; i < 4; ++i) {
                const int mrow = m0 + wm + i * 16 + lq * 4;
                #pragma unroll
                for (int r = 0; r < 4; ++r)
                    dst[(size_t)(mrow + r) * H_DIM + ng] =
                        (_Float16)(acc[i][j][r] + bv);
            }
        }
    } else {
        #pragma unroll
        for (int j = 0; j < 4; ++j) {
            const int ng = ng0 + wn + j * 16 + lr;
            const float bv = bias[ng];
            #pragma unroll
            for (int i = 0; i < 4; ++i) {
                const int mrow = m0 + wm + i * 16 + lq * 4;
                #pragma unroll
                for (int r = 0; r < 4; ++r)
                    Xm[(size_t)(mrow + r) * H_DIM + ng] = acc[i][j][r] + bv;
            }
        }
    }
}

// ---------------------------------------------------------------------------
// Phase 2: persistent recurrence, one WG per batch element (256 WGs = 256 CUs).
// Thread (g = tid>>2, s = tid&3) handles rows g and g+128 with k-slice
// [64s, 64s+64) of the h-half of the weights:
//   phase A: partials of z_g, r_g, z_{g+128}, r_{g+128}  (4 outputs / read)
//   phase B: partials of m_g, m_{g+128}
// Quad reduction via DPP quad_perm (VALU). k-chunk order is XOR-rotated per
// lane (kk ^ 2s) so the 4 concurrent b128 LDS addresses hit disjoint bank
// quads (conflict-free). z and old-h live in registers of the finalizing
// lane; h crosses to the r-lane by one DPP. LDS: hh (h f16) + rh (r*h f16).
// __launch_bounds__(512, 1): CUDA minBlocks semantics => VGPR cap 256, so
// the 192 weight VGPRs stay resident (the (512,2) variant capped at 128 and
// rematerialized weight loads every step).
// ---------------------------------------------------------------------------
__global__ __launch_bounds__(512, 1) void gru_rec(
    const float* __restrict__ Wz,
    const float* __restrict__ Wr,
    const float* __restrict__ Wm,
    const _Float16* __restrict__ Xz,
    const _Float16* __restrict__ Xr,
    float* __restrict__ out)   // holds Xm+bm on entry per row; overwritten
{
    const int b = blockIdx.x;
    const int t = threadIdx.x;
    const int g = t >> 2;            // 0..127
    const int s = t & 3;             // k-slice index
    const int rowA = g;
    const int rowB = g + 128;
    const int col = g + ((s & 2) << 6);   // g (s=0,1) or g+128 (s=2,3)

    __shared__ __align__(16) _Float16 hh[256];  // h (f16) broadcast buffer
    __shared__ __align__(16) _Float16 rh[256];  // r*h (f16)

    // ---- load recurrent weights (h-half, k-slice [64s,64s+64)) -> f16 regs
    // storage index kk corresponds to local chunk lk = kk ^ 2s (bank rotation)
    half2_t wzA[32], wzB[32], wrA[32], wrB[32], wmA[32], wmB[32];
    {
        const size_t sb = 256 + 64 * s;
        const float4* pzA = (const float4*)(Wz + (size_t)rowA * 512 + sb);
        const float4* pzB = (const float4*)(Wz + (size_t)rowB * 512 + sb);
        const float4* prA = (const float4*)(Wr + (size_t)rowA * 512 + sb);
        const float4* prB = (const float4*)(Wr + (size_t)rowB * 512 + sb);
        const float4* pmA = (const float4*)(Wm + (size_t)rowA * 512 + sb);
        const float4* pmB = (const float4*)(Wm + (size_t)rowB * 512 + sb);
        #pragma unroll
        for (int kk = 0; kk < 8; ++kk) {
            const int lk = kk ^ (s << 1);
            float4 f0, f1;
            f0 = pzA[2*lk]; f1 = pzA[2*lk+1];
            wzA[4*kk]=cvt2(f0.x,f0.y); wzA[4*kk+1]=cvt2(f0.z,f0.w);
            wzA[4*kk+2]=cvt2(f1.x,f1.y); wzA[4*kk+3]=cvt2(f1.z,f1.w);
            f0 = pzB[2*lk]; f1 = pzB[2*lk+1];
            wzB[4*kk]=cvt2(f0.x,f0.y); wzB[4*kk+1]=cvt2(f0.z,f0.w);
            wzB[4*kk+2]=cvt2(f1.x,f1.y); wzB[4*kk+3]=cvt2(f1.z,f1.w);
            f0 = prA[2*lk]; f1 = prA[2*lk+1];
            wrA[4*kk]=cvt2(f0.x,f0.y); wrA[4*kk+1]=cvt2(f0.z,f0.w);
            wrA[4*kk+2]=cvt2(f1.x,f1.y); wrA[4*kk+3]=cvt2(f1.z,f1.w);
            f0 = prB[2*lk]; f1 = prB[2*lk+1];
            wrB[4*kk]=cvt2(f0.x,f0.y); wrB[4*kk+1]=cvt2(f0.z,f0.w);
            wrB[4*kk+2]=cvt2(f1.x,f1.y); wrB[4*kk+3]=cvt2(f1.z,f1.w);
            f0 = pmA[2*lk]; f1 = pmA[2*lk+1];
            wmA[4*kk]=cvt2(f0.x,f0.y); wmA[4*kk+1]=cvt2(f0.z,f0.w);
            wmA[4*kk+2]=cvt2(f1.x,f1.y); wmA[4*kk+3]=cvt2(f1.z,f1.w);
            f0 = pmB[2*lk]; f1 = pmB[2*lk+1];
            wmB[4*kk]=cvt2(f0.x,f0.y); wmB[4*kk+1]=cvt2(f0.z,f0.w);
            wmB[4*kk+2]=cvt2(f1.x,f1.y); wmB[4*kk+3]=cvt2(f1.z,f1.w);
        }
    }

    if (t < 256) hh[t] = (_Float16)0.0f;
    __syncthreads();

    // LDS read bases for this thread's k-slice; per-kk byte offsets
    // (kk*16) ^ (s*32) are loop-invariant -> hoisted into registers.
    const char* hbase = (const char*)hh + s * 128;
    const char* rbase = (const char*)rh + s * 128;

    const size_t rowbase = (size_t)b * T_DIM * H_DIM;
    const _Float16* xgp = (s & 1) ? Xr : Xz;   // gate-input source per lane

    float hown = 0.0f;   // even lanes: h[col] master copy (f32)
    float zown = 0.0f;   // even lanes: z gate value for col

    // step-0 prefetch
    float xg_n = (float)xgp[rowbase + col];
    float xm_n = (s & 1) ? 0.0f : out[rowbase + col];

    #pragma unroll 1
    for (int ts = 0; ts < T_DIM; ++ts) {
        const float xg = xg_n;
        const float xm = xm_n;
        if (ts + 1 < T_DIM) {
            const size_t nb = rowbase + (size_t)(ts + 1) * H_DIM;
            xg_n = (float)xgp[nb + col];
            xm_n = (s & 1) ? 0.0f : out[nb + col];
        }

        // ---- phase A: 4-output-fused partial dots over hh k-slice ----
        float az = 0.f, ar = 0.f, zb = 0.f, rb = 0.f;
        #pragma unroll
        for (int kk = 0; kk < 8; ++kk) {
            half8_t hv = *(const half8_t*)(hbase + ((kk * 16) ^ (s * 32)));
            half2_t p0 = __builtin_shufflevector(hv, hv, 0, 1);
            half2_t p1 = __builtin_shufflevector(hv, hv, 2, 3);
            half2_t p2 = __builtin_shufflevector(hv, hv, 4, 5);
            half2_t p3 = __builtin_shufflevector(hv, hv, 6, 7);
            az = fdot2f(wzA[4*kk],   p0, az); az = fdot2f(wzA[4*kk+1], p1, az);
            az = fdot2f(wzA[4*kk+2], p2, az); az = fdot2f(wzA[4*kk+3], p3, az);
            ar = fdot2f(wrA[4*kk],   p0, ar); ar = fdot2f(wrA[4*kk+1], p1, ar);
            ar = fdot2f(wrA[4*kk+2], p2, ar); ar = fdot2f(wrA[4*kk+3], p3, ar);
            zb = fdot2f(wzB[4*kk],   p0, zb); zb = fdot2f(wzB[4*kk+1], p1, zb);
            zb = fdot2f(wzB[4*kk+2], p2, zb); zb = fdot2f(wzB[4*kk+3], p3, zb);
            rb = fdot2f(wrB[4*kk],   p0, rb); rb = fdot2f(wrB[4*kk+1], p1, rb);
            rb = fdot2f(wrB[4*kk+2], p2, rb); rb = fdot2f(wrB[4*kk+3], p3, rb);
        }
        // quad reduction (DPP, VALU-only)
        az += dpp_xor1(az); az += dpp_xor2(az);
        ar += dpp_xor1(ar); ar += dpp_xor2(ar);
        zb += dpp_xor1(zb); zb += dpp_xor2(zb);
        rb += dpp_xor1(rb); rb += dpp_xor2(rb);
        // lane s finalizes: s=0 -> z_A, s=1 -> r_A, s=2 -> z_B, s=3 -> r_B
        const float d01 = (s & 1) ? ar : az;
        const float d23 = (s & 1) ? rb : zb;
        const float dsum = (s & 2) ? d23 : d01;
        const float gate = fast_rcp(1.0f + __expf(-(dsum + xg)));
        const float hpair = dpp_xor1(hown);     // r-lane gets partner's h
        if (s & 1) rh[col] = (_Float16)(gate * hpair);
        else       zown = gate;
        __syncthreads();

        // ---- phase B: 2-output-fused partial dots over rh k-slice ----
        float ca = 0.f, cb = 0.f;
        #pragma unroll
        for (int kk = 0; kk < 8; ++kk) {
            half8_t rv = *(const half8_t*)(rbase + ((kk * 16) ^ (s * 32)));
            half2_t p0 = __builtin_shufflevector(rv, rv, 0, 1);
            half2_t p1 = __builtin_shufflevector(rv, rv, 2, 3);
            half2_t p2 = __builtin_shufflevector(rv, rv, 4, 5);
            half2_t p3 = __builtin_shufflevector(rv, rv, 6, 7);
            ca = fdot2f(wmA[4*kk],   p0, ca); ca = fdot2f(wmA[4*kk+1], p1, ca);
            ca = fdot2f(wmA[4*kk+2], p2, ca); ca = fdot2f(wmA[4*kk+3], p3, ca);
            cb = fdot2f(wmB[4*kk],   p0, cb); cb = fdot2f(wmB[4*kk+1], p1, cb);
            cb = fdot2f(wmB[4*kk+2], p2, cb); cb = fdot2f(wmB[4*kk+3], p3, cb);
        }
        ca += dpp_xor1(ca); ca += dpp_xor2(ca);
        cb += dpp_xor1(cb); cb += dpp_xor2(cb);
        if (!(s & 1)) {     // even lanes finalize h for `col`
            const float am = ((s & 2) ? cb : ca) + xm;   // + Xm + bm
            const float hcand = 1.0f - 2.0f * fast_rcp(1.0f + __expf(2.0f * am));
            const float hn = (1.0f - zown) * hown + zown * hcand;
            out[rowbase + (size_t)ts * H_DIM + col] = hn;
            hown = hn;
            hh[col] = (_Float16)hn;
        }
        __syncthreads();
    }
}

extern "C" void kernel_launch(void* const* d_in, const int* in_sizes, int n_in,
                              void* d_out, int out_size, void* d_ws, size_t ws_size,
                              hipStream_t stream) {
    (void)in_sizes; (void)n_in; (void)out_size; (void)ws_size;
    const float* emb = (const float*)d_in[0];
    const float* Wz  = (const float*)d_in[1];
    const float* bz  = (const float*)d_in[2];
    const float* Wr  = (const float*)d_in[3];
    const float* br  = (const float*)d_in[4];
    const float* Wm  = (const float*)d_in[5];
    const float* bm  = (const float*)d_in[6];
    float* out = (float*)d_out;

    _Float16* Xz = (_Float16*)d_ws;                      // [131072][256] f16
    _Float16* Xr = Xz + (size_t)MROWS * H_DIM;           // [131072][256] f16

    dim3 g1(6, MROWS / 128);
    gemm_x<<<g1, 256, 0, stream>>>(emb, Wz, bz, Wr, br, Wm, bm, Xz, Xr, out);
    gru_rec<<<B_DIM, 512, 0, stream>>>(Wz, Wr, Wm, Xz, Xr, out);
}

// Round 3
// 1258.709 us; speedup vs baseline: 1.0077x; 1.0077x over previous
//
#include <hip/hip_runtime.h>

typedef _Float16 half8_t __attribute__((ext_vector_type(8)));
typedef _Float16 half2_t __attribute__((ext_vector_type(2)));
typedef float floatx4 __attribute__((ext_vector_type(4)));

#define B_DIM 256
#define T_DIM 512
#define E_DIM 256
#define H_DIM 256
#define MROWS (B_DIM * T_DIM)  // 131072 rows of [B*T, E]

__device__ __forceinline__ float fdot2f(half2_t a, half2_t b, float c) {
#if __has_builtin(__builtin_amdgcn_fdot2)
    return __builtin_amdgcn_fdot2(a, b, c, false);
#else
    return c + (float)a[0] * (float)b[0] + (float)a[1] * (float)b[1];
#endif
}

// quad_perm DPP cross-lane (within each group of 4 lanes) — VALU, no LDS pipe.
__device__ __forceinline__ float dpp_xor1(float x) {
#if __has_builtin(__builtin_amdgcn_mov_dpp)
    int i = __builtin_bit_cast(int, x);
    i = __builtin_amdgcn_mov_dpp(i, 0xB1, 0xF, 0xF, true);  // [1,0,3,2]
    return __builtin_bit_cast(float, i);
#else
    return __shfl_xor(x, 1);
#endif
}
__device__ __forceinline__ float dpp_xor2(float x) {
#if __has_builtin(__builtin_amdgcn_mov_dpp)
    int i = __builtin_bit_cast(int, x);
    i = __builtin_amdgcn_mov_dpp(i, 0x4E, 0xF, 0xF, true);  // [2,3,0,1]
    return __builtin_bit_cast(float, i);
#else
    return __shfl_xor(x, 2);
#endif
}

__device__ __forceinline__ float fast_rcp(float x) {
#if __has_builtin(__builtin_amdgcn_rcpf)
    return __builtin_amdgcn_rcpf(x);
#else
    return 1.0f / x;
#endif
}

// pack two float4 (8 consecutive floats) into one half8_t (4 VGPRs)
__device__ __forceinline__ half8_t cvt8(const float4* p) {
    float4 a = p[0], b = p[1];
    half8_t v;
    v[0] = (_Float16)a.x; v[1] = (_Float16)a.y;
    v[2] = (_Float16)a.z; v[3] = (_Float16)a.w;
    v[4] = (_Float16)b.x; v[5] = (_Float16)b.y;
    v[6] = (_Float16)b.z; v[7] = (_Float16)b.w;
    return v;
}

// ---------------------------------------------------------------------------
// Phase 1: X[m][n] = emb[m][:E] . Wg[n][:E] + bg[n]  for gates g in {z,r,m}
//   gate 0 -> Xz (f16, ws), gate 1 -> Xr (f16, ws), gate 2 -> Xm (f32, d_out)
// ---------------------------------------------------------------------------
__global__ __launch_bounds__(256, 2) void gemm_x(
    const float* __restrict__ emb,
    const float* __restrict__ Wz, const float* __restrict__ bz,
    const float* __restrict__ Wr, const float* __restrict__ br,
    const float* __restrict__ Wm, const float* __restrict__ bm,
    _Float16* __restrict__ Xz, _Float16* __restrict__ Xr,
    float* __restrict__ Xm)
{
    const int n0 = blockIdx.x * 128;
    const int m0 = blockIdx.y * 128;
    const int gate = n0 >> 8;
    const int ng0 = n0 & 255;
    const float* W    = (gate == 0) ? Wz : (gate == 1) ? Wr : Wm;
    const float* bias = (gate == 0) ? bz : (gate == 1) ? br : bm;

    __shared__ __align__(16) _Float16 lA[128 * 40];
    __shared__ __align__(16) _Float16 lB[128 * 40];

    const int t = threadIdx.x;
    const int lane = t & 63;
    const int wave = t >> 6;
    const int wm = (wave >> 1) * 64;
    const int wn = (wave & 1) * 64;
    const int lq = lane >> 4;
    const int lr = lane & 15;

    floatx4 acc[4][4];
    #pragma unroll
    for (int i = 0; i < 4; ++i)
        #pragma unroll
        for (int j = 0; j < 4; ++j)
            acc[i][j] = (floatx4)0.0f;

    const int srow = t >> 1;
    const int scol = (t & 1) * 16;
    const float* aSrc = emb + (size_t)(m0 + srow) * E_DIM + scol;
    const float* bSrc = W + (size_t)(ng0 + srow) * (E_DIM + H_DIM) + scol;

    for (int k0 = 0; k0 < E_DIM; k0 += 32) {
        float ta[16], tb[16];
        #pragma unroll
        for (int u = 0; u < 4; ++u) {
            *(float4*)(ta + 4 * u) = *(const float4*)(aSrc + k0 + 4 * u);
            *(float4*)(tb + 4 * u) = *(const float4*)(bSrc + k0 + 4 * u);
        }
        half8_t a0, a1, b0, b1;
        #pragma unroll
        for (int u = 0; u < 8; ++u) {
            a0[u] = (_Float16)ta[u]; a1[u] = (_Float16)ta[u + 8];
            b0[u] = (_Float16)tb[u]; b1[u] = (_Float16)tb[u + 8];
        }
        __syncthreads();
        *(half8_t*)&lA[srow * 40 + scol]     = a0;
        *(half8_t*)&lA[srow * 40 + scol + 8] = a1;
        *(half8_t*)&lB[srow * 40 + scol]     = b0;
        *(half8_t*)&lB[srow * 40 + scol + 8] = b1;
        __syncthreads();

        half8_t af[4], bf[4];
        #pragma unroll
        for (int i = 0; i < 4; ++i)
            af[i] = *(const half8_t*)&lA[(wm + i * 16 + lr) * 40 + lq * 8];
        #pragma unroll
        for (int j = 0; j < 4; ++j)
            bf[j] = *(const half8_t*)&lB[(wn + j * 16 + lr) * 40 + lq * 8];
        #pragma unroll
        for (int i = 0; i < 4; ++i)
            #pragma unroll
            for (int j = 0; j < 4; ++j)
                acc[i][j] = __builtin_amdgcn_mfma_f32_16x16x32_f16(
                    af[i], bf[j], acc[i][j], 0, 0, 0);
    }

    if (gate < 2) {
        _Float16* dst = (gate == 0) ? Xz : Xr;
        #pragma unroll
        for (int j = 0; j < 4; ++j) {
            const int ng = ng0 + wn + j * 16 + lr;
            const float bv = bias[ng];
            #pragma unroll
            for (int i = 0; i < 4; ++i) {
                const int mrow = m0 + wm + i * 16 + lq * 4;
                #pragma unroll
                for (int r = 0; r < 4; ++r)
                    dst[(size_t)(mrow + r) * H_DIM + ng] =
                        (_Float16)(acc[i][j][r] + bv);
            }
        }
    } else {
        #pragma unroll
        for (int j = 0; j < 4; ++j) {
            const int ng = ng0 + wn + j * 16 + lr;
            const float bv = bias[ng];
            #pragma unroll
            for (int i = 0; i < 4; ++i) {
                const int mrow = m0 + wm + i * 16 + lq * 4;
                #pragma unroll
                for (int r = 0; r < 4; ++r)
                    Xm[(size_t)(mrow + r) * H_DIM + ng] = acc[i][j][r] + bv;
            }
        }
    }
}

// ---------------------------------------------------------------------------
// Phase 2: persistent recurrence, one WG per batch element (256 WGs = 256 CUs).
// Thread (g = tid>>2, s = tid&3): rows g and g+128, k-slice [64s,64s+64).
// Weights held in 48 NAMED half8_t SSA values (192 VGPRs) — hand-scalarized
// because array-form was demoted to scratch (R2: VGPR_Count=128, +63MB
// scratch writes, weights re-fetched from L2 every step => 976us).
// amdgpu_waves_per_eu(2,2): 8 waves/block = exactly 2/EU anyway; pinning it
// sets the allocator budget to 256 VGPRs so it has no reason to spill.
// Each half2 operand of v_dot2_f32_f16 is one source VGPR (shufflevector of
// lanes [2i,2i+1] of a half8 is a zero-cost register select).
// ---------------------------------------------------------------------------
#define SV2(V, I) __builtin_shufflevector(V, V, 2 * (I), 2 * (I) + 1)

#define DOT8(acc, W, p0, p1, p2, p3)          \
    acc = fdot2f(SV2(W, 0), p0, acc);         \
    acc = fdot2f(SV2(W, 1), p1, acc);         \
    acc = fdot2f(SV2(W, 2), p2, acc);         \
    acc = fdot2f(SV2(W, 3), p3, acc);

#define DECL8(V) half8_t V##0, V##1, V##2, V##3, V##4, V##5, V##6, V##7
#define LDW(V, P)                             \
    V##0 = cvt8((P) + 2 * (0 ^ s2));          \
    V##1 = cvt8((P) + 2 * (1 ^ s2));          \
    V##2 = cvt8((P) + 2 * (2 ^ s2));          \
    V##3 = cvt8((P) + 2 * (3 ^ s2));          \
    V##4 = cvt8((P) + 2 * (4 ^ s2));          \
    V##5 = cvt8((P) + 2 * (5 ^ s2));          \
    V##6 = cvt8((P) + 2 * (6 ^ s2));          \
    V##7 = cvt8((P) + 2 * (7 ^ s2));

#define CHUNK_A(K) {                                                   \
    half8_t hv = *(const half8_t*)(hbase + ((K * 16) ^ sx));           \
    half2_t p0 = SV2(hv, 0), p1 = SV2(hv, 1);                          \
    half2_t p2 = SV2(hv, 2), p3 = SV2(hv, 3);                          \
    DOT8(az, zA##K, p0, p1, p2, p3);                                   \
    DOT8(ar, rA##K, p0, p1, p2, p3);                                   \
    DOT8(zb, zB##K, p0, p1, p2, p3);                                   \
    DOT8(rb, rB##K, p0, p1, p2, p3); }

#define CHUNK_B(K) {                                                   \
    half8_t rv = *(const half8_t*)(rbase + ((K * 16) ^ sx));           \
    half2_t p0 = SV2(rv, 0), p1 = SV2(rv, 1);                          \
    half2_t p2 = SV2(rv, 2), p3 = SV2(rv, 3);                          \
    DOT8(ca, mA##K, p0, p1, p2, p3);                                   \
    DOT8(cb, mB##K, p0, p1, p2, p3); }

__global__ __launch_bounds__(512)
__attribute__((amdgpu_waves_per_eu(2, 2))) void gru_rec(
    const float* __restrict__ Wz,
    const float* __restrict__ Wr,
    const float* __restrict__ Wm,
    const _Float16* __restrict__ Xz,
    const _Float16* __restrict__ Xr,
    float* __restrict__ out)   // holds Xm+bm on entry per row; overwritten
{
    const int b = blockIdx.x;
    const int t = threadIdx.x;
    const int g = t >> 2;                 // 0..127
    const int s = t & 3;                  // k-slice index
    const int s2 = s << 1;                // bank-rotation chunk xor
    const int sx = s << 5;                // byte xor for LDS chunk addresses
    const int rowA = g;
    const int rowB = g + 128;
    const int col = g + ((s & 2) << 6);   // g (s=0,1) or g+128 (s=2,3)

    __shared__ __align__(16) _Float16 hh[256];  // h (f16) broadcast buffer
    __shared__ __align__(16) _Float16 rh[256];  // r*h (f16)

    // ---- recurrent weights (h-half, k-slice [64s,64s+64)) -> named regs ----
    DECL8(zA); DECL8(zB); DECL8(rA); DECL8(rB); DECL8(mA); DECL8(mB);
    {
        const size_t sb = 256 + 64 * (size_t)s;
        const float4* pzA = (const float4*)(Wz + (size_t)rowA * 512 + sb);
        const float4* pzB = (const float4*)(Wz + (size_t)rowB * 512 + sb);
        const float4* prA = (const float4*)(Wr + (size_t)rowA * 512 + sb);
        const float4* prB = (const float4*)(Wr + (size_t)rowB * 512 + sb);
        const float4* pmA = (const float4*)(Wm + (size_t)rowA * 512 + sb);
        const float4* pmB = (const float4*)(Wm + (size_t)rowB * 512 + sb);
        LDW(zA, pzA); LDW(zB, pzB);
        LDW(rA, prA); LDW(rB, prB);
        LDW(mA, pmA); LDW(mB, pmB);
    }

    if (t < 256) hh[t] = (_Float16)0.0f;
    __syncthreads();

    const char* hbase = (const char*)hh + s * 128;
    const char* rbase = (const char*)rh + s * 128;

    const size_t rowbase = (size_t)b * T_DIM * H_DIM;
    const _Float16* xgp = (s & 1) ? Xr : Xz;   // gate-input source per lane

    float hown = 0.0f;   // even lanes: h[col] master copy (f32)
    float zown = 0.0f;   // even lanes: z gate value for col

    float xg_n = (float)xgp[rowbase + col];
    float xm_n = (s & 1) ? 0.0f : out[rowbase + col];

    #pragma unroll 1
    for (int ts = 0; ts < T_DIM; ++ts) {
        const float xg = xg_n;
        const float xm = xm_n;
        if (ts + 1 < T_DIM) {
            const size_t nb = rowbase + (size_t)(ts + 1) * H_DIM;
            xg_n = (float)xgp[nb + col];
            xm_n = (s & 1) ? 0.0f : out[nb + col];
        }

        // ---- phase A: 4-output-fused partial dots over hh k-slice ----
        float az = 0.f, ar = 0.f, zb = 0.f, rb = 0.f;
        CHUNK_A(0) CHUNK_A(1) CHUNK_A(2) CHUNK_A(3)
        CHUNK_A(4) CHUNK_A(5) CHUNK_A(6) CHUNK_A(7)
        az += dpp_xor1(az); az += dpp_xor2(az);
        ar += dpp_xor1(ar); ar += dpp_xor2(ar);
        zb += dpp_xor1(zb); zb += dpp_xor2(zb);
        rb += dpp_xor1(rb); rb += dpp_xor2(rb);
        // lane s finalizes: s=0 -> z_A, s=1 -> r_A, s=2 -> z_B, s=3 -> r_B
        const float d01 = (s & 1) ? ar : az;
        const float d23 = (s & 1) ? rb : zb;
        const float dsum = (s & 2) ? d23 : d01;
        const float gate = fast_rcp(1.0f + __expf(-(dsum + xg)));
        const float hpair = dpp_xor1(hown);     // r-lane gets partner's h
        if (s & 1) rh[col] = (_Float16)(gate * hpair);
        else       zown = gate;
        __syncthreads();

        // ---- phase B: 2-output-fused partial dots over rh k-slice ----
        float ca = 0.f, cb = 0.f;
        CHUNK_B(0) CHUNK_B(1) CHUNK_B(2) CHUNK_B(3)
        CHUNK_B(4) CHUNK_B(5) CHUNK_B(6) CHUNK_B(7)
        ca += dpp_xor1(ca); ca += dpp_xor2(ca);
        cb += dpp_xor1(cb); cb += dpp_xor2(cb);
        if (!(s & 1)) {     // even lanes finalize h for `col`
            const float am = ((s & 2) ? cb : ca) + xm;   // + Xm + bm
            const float hcand = 1.0f - 2.0f * fast_rcp(1.0f + __expf(2.0f * am));
            const float hn = (1.0f - zown) * hown + zown * hcand;
            out[rowbase + (size_t)ts * H_DIM + col] = hn;
            hown = hn;
            hh[col] = (_Float16)hn;
        }
        __syncthreads();
    }
}

extern "C" void kernel_launch(void* const* d_in, const int* in_sizes, int n_in,
                              void* d_out, int out_size, void* d_ws, size_t ws_size,
                              hipStream_t stream) {
    (void)in_sizes; (void)n_in; (void)out_size; (void)ws_size;
    const float* emb = (const float*)d_in[0];
    const float* Wz  = (const float*)d_in[1];
    const float* bz  = (const float*)d_in[2];
    const float* Wr  = (const float*)d_in[3];
    const float* br  = (const float*)d_in[4];
    const float* Wm  = (const float*)d_in[5];
    const float* bm  = (const float*)d_in[6];
    float* out = (float*)d_out;

    _Float16* Xz = (_Float16*)d_ws;                      // [131072][256] f16
    _Float16* Xr = Xz + (size_t)MROWS * H_DIM;           // [131072][256] f16

    dim3 g1(6, MROWS / 128);
    gemm_x<<<g1, 256, 0, stream>>>(emb, Wz, bz, Wr, br, Wm, bm, Xz, Xr, out);
    gru_rec<<<B_DIM, 512, 0, stream>>>(Wz, Wr, Wm, Xz, Xr, out);
}